// Round 3
// baseline (4682.162 us; speedup 1.0000x reference)
//
#include <hip/hip_runtime.h>
#include <hip/hip_bf16.h>

#define ITER_TIME 32
#define DECAY 0.9f

typedef __attribute__((ext_vector_type(8))) short short8;
typedef __attribute__((ext_vector_type(4))) float f32x4;
typedef unsigned short ushort_t;
typedef unsigned int u32;

// global -> LDS direct DMA, 16B per lane. Dest is wave-uniform base + lane*16.
__device__ __forceinline__ void gload16(const ushort_t* g, ushort_t* l) {
    __builtin_amdgcn_global_load_lds(
        (const __attribute__((address_space(1))) u32*)g,
        (__attribute__((address_space(3))) u32*)l, 16, 0, 0);
}

// ---------------------------------------------------------------------------
// Convert f32 -> bf16 elementwise (for x). Block 0 also zeroes the 68
// per-tile fixup counters.
// ---------------------------------------------------------------------------
__global__ void conv_f32_bf16(const float* __restrict__ in,
                              __hip_bfloat16* __restrict__ out, int n,
                              int* __restrict__ cnt) {
    if (blockIdx.x == 0 && threadIdx.x < 68) cnt[threadIdx.x] = 0;
    int i = blockIdx.x * 256 + threadIdx.x;
    if (i < n) out[i] = __float2bfloat16(in[i]);
}

// ---------------------------------------------------------------------------
// Fused convert + transpose: f32 in [R][C] -> bf16 out [C][R]
// ---------------------------------------------------------------------------
__global__ void transpose_f32_bf16(const float* __restrict__ in,
                                   __hip_bfloat16* __restrict__ out, int R,
                                   int C) {
    __shared__ float tile[32][33];
    int tx = threadIdx.x, ty = threadIdx.y;
    size_t x = blockIdx.x * 32 + tx;  // col in `in`
    size_t y = blockIdx.y * 32 + ty;  // row in `in`
    tile[ty][tx] = in[y * C + x];
    __syncthreads();
    size_t ox = blockIdx.y * 32 + tx;  // col in `out` (= row in `in`)
    size_t oy = blockIdx.x * 32 + ty;  // row in `out` (= col in `in`)
    out[oy * R + ox] = __float2bfloat16(tile[tx][ty]);
}

// ---------------------------------------------------------------------------
// i_ = x @ W_i with fused t=0 elementwise epilogue:
//   i_ = acc + bias (biased drive, reused every step)
//   u0 = i_ ; act[:,0,:] = u0 ; a0 = relu(u0) (bf16)
// grid (2, 32), block 256. Same staging/swizzle/dbuf structure as gemm_step.
// ---------------------------------------------------------------------------
__global__ __launch_bounds__(256)
void gemm_wi(const ushort_t* __restrict__ A,   // [256][1024] bf16
             const ushort_t* __restrict__ BT,  // [4096][1024] bf16
             const float* __restrict__ bias, float* __restrict__ i_,
             float* __restrict__ u, __hip_bfloat16* __restrict__ a0,
             float* __restrict__ act, int K) {
    __shared__ __attribute__((aligned(16))) ushort_t As[2][128 * 64];
    __shared__ __attribute__((aligned(16))) ushort_t Bs[2][128 * 64];

    int m0 = blockIdx.x * 128;
    int by = blockIdx.y;
    const ushort_t* Bsrc = BT + (size_t)by * 128 * K;

    int t = threadIdx.x;
    int wave = t >> 6, lane = t & 63;
    int quad = lane >> 4, l16 = lane & 15;
    int wm = (wave >> 1) * 64, wn = (wave & 1) * 64;

    int lr = lane >> 3;
    int lcol = ((lane & 7) ^ lr) << 3;
    const ushort_t* aBase = A + (size_t)(m0 + wave * 32 + lr) * K + lcol;
    const ushort_t* bBase = Bsrc + (size_t)(wave * 32 + lr) * K + lcol;

    f32x4 acc[4][4];
#pragma unroll
    for (int i = 0; i < 4; i++)
#pragma unroll
        for (int j = 0; j < 4; j++) acc[i][j] = (f32x4){0.f, 0.f, 0.f, 0.f};

    int nt = K >> 6;
    int swz = (l16 & 7) << 3;

    auto stage = [&](int buf, int kk) {
#pragma unroll
        for (int i = 0; i < 4; ++i) {
            gload16(aBase + (size_t)(i * 8) * K + kk,
                    &As[buf][(wave * 4 + i) * 512]);
            gload16(bBase + (size_t)(i * 8) * K + kk,
                    &Bs[buf][(wave * 4 + i) * 512]);
        }
    };

    stage(0, 0);
    __syncthreads();
    int cur = 0;
    for (int it = 0; it < nt; ++it) {
        if (it + 1 < nt) stage(cur ^ 1, (it + 1) * 64);
#pragma unroll
        for (int kstep = 0; kstep < 2; ++kstep) {
            int ko = kstep * 32 + quad * 8;
            int pc = ko ^ swz;
            short8 af[4], bfr[4];
#pragma unroll
            for (int i = 0; i < 4; i++)
                af[i] = *(const short8*)&As[cur][(wm + i * 16 + l16) * 64 + pc];
#pragma unroll
            for (int j = 0; j < 4; j++)
                bfr[j] = *(const short8*)&Bs[cur][(wn + j * 16 + l16) * 64 + pc];
#pragma unroll
            for (int i = 0; i < 4; i++)
#pragma unroll
                for (int j = 0; j < 4; j++)
                    acc[i][j] = __builtin_amdgcn_mfma_f32_16x16x32_bf16(
                        af[i], bfr[j], acc[i][j], 0, 0, 0);
        }
        __syncthreads();
        cur ^= 1;
    }

    // Fused t=0 epilogue. C/D layout: col = lane&15, row = quad*4 + reg.
#pragma unroll
    for (int i = 0; i < 4; i++)
#pragma unroll
        for (int j = 0; j < 4; j++) {
            int gcol = by * 128 + wn + j * 16 + l16;
#pragma unroll
            for (int rr = 0; rr < 4; ++rr) {
                int grow = m0 + wm + i * 16 + quad * 4 + rr;
                size_t p = (size_t)grow * 4096 + gcol;
                float iv = acc[i][j][rr] + bias[gcol];
                i_[p] = iv;
                u[p] = iv;
                __builtin_nontemporal_store(
                    iv, &act[(size_t)grow * (ITER_TIME * 4096) + gcol]);
                float ar = iv > 0.f ? iv : 0.f;
                a0[p] = __float2bfloat16(ar);
            }
        }
}

// ---------------------------------------------------------------------------
// One recurrence step, single kernel: split-K GEMM a_t @ [W_r|W_f] with
// stream-K fixup. Non-last ks-blocks write thread-indexed f32x4 partials
// (pbuf[ks][tile][16][256], coalesced 4KB stores) and exit. The LAST block
// per tile (device-scope atomic counter, no spin) reduces the partials
// (L2-hot, same XCD thanks to the block swizzle) and runs the fused
// elementwise epilogue:
//   W_r tiles: u_{t+1} = DECAY*u_t + i_ + r ; act[:,t+1] ; a_{t+1} = relu
//   W_f tiles: out[:,t] = f
// Block mapping (only_f==0), grid 68*KS, TPB=2*KS blocks per tile:
//   xcd = blk&7 (round-robin dispatch) ; j = blk>>3
//   j <  4*TPB : by = xcd + 8*(j/TPB)  (4 W_r column-groups pinned per XCD)
//   j >= 4*TPB : W_f tiles (by 32,33) spread across XCDs
// ---------------------------------------------------------------------------
template <int KS>
__global__ __launch_bounds__(256)
void gemm_step(const ushort_t* __restrict__ A,   // a_t [256][4096] bf16
               const ushort_t* __restrict__ BT,  // [4352][4096] bf16 (Wr|Wf)
               f32x4* __restrict__ pbuf,         // [KS][68][16][256] f32x4
               int* __restrict__ cnt,            // [68]
               const float* __restrict__ i_, float* __restrict__ u,
               __hip_bfloat16* __restrict__ a_out, float* __restrict__ out,
               float* __restrict__ act, const int t, const int only_f) {
    constexpr int TPB = 2 * KS;
    const int K = 4096;
    constexpr int klen = 4096 / KS;
    __shared__ __attribute__((aligned(16))) ushort_t As[2][128 * 64];
    __shared__ __attribute__((aligned(16))) ushort_t Bs[2][128 * 64];
    __shared__ int s_last;

    int blk = blockIdx.x;
    int m, by, ks;
    if (only_f) {
        by = 32 + blk / TPB;
        int w = blk % TPB;
        m = w & 1;
        ks = w >> 1;
    } else {
        int xcd = blk & 7, j = blk >> 3, w;
        if (j < 4 * TPB) {
            by = xcd + 8 * (j / TPB);
            w = j % TPB;
        } else {
            int idx = (j - 4 * TPB) + (TPB / 4) * xcd;
            by = 32 + idx / TPB;
            w = idx % TPB;
        }
        m = w & 1;
        ks = w >> 1;
    }
    int tile = by * 2 + m;
    int m0 = m * 128;
    const ushort_t* Bsrc = BT + (size_t)by * 128 * K;

    int tid = threadIdx.x;
    int wave = tid >> 6, lane = tid & 63;
    int quad = lane >> 4, l16 = lane & 15;
    int wm = (wave >> 1) * 64, wn = (wave & 1) * 64;

    int lr = lane >> 3;
    int lcol = ((lane & 7) ^ lr) << 3;
    const ushort_t* aBase = A + (size_t)(m0 + wave * 32 + lr) * K + lcol;
    const ushort_t* bBase = Bsrc + (size_t)(wave * 32 + lr) * K + lcol;

    f32x4 acc[4][4];
#pragma unroll
    for (int i = 0; i < 4; i++)
#pragma unroll
        for (int j = 0; j < 4; j++) acc[i][j] = (f32x4){0.f, 0.f, 0.f, 0.f};

    const int k0 = ks * klen;
    constexpr int nt = klen >> 6;
    int swz = (l16 & 7) << 3;

    auto stage = [&](int buf, int kk) {
#pragma unroll
        for (int i = 0; i < 4; ++i) {
            gload16(aBase + (size_t)(i * 8) * K + kk,
                    &As[buf][(wave * 4 + i) * 512]);
            gload16(bBase + (size_t)(i * 8) * K + kk,
                    &Bs[buf][(wave * 4 + i) * 512]);
        }
    };

    stage(0, k0);
    __syncthreads();
    int cur = 0;
    for (int it = 0; it < nt; ++it) {
        if (it + 1 < nt) stage(cur ^ 1, k0 + (it + 1) * 64);
#pragma unroll
        for (int kstep = 0; kstep < 2; ++kstep) {
            int ko = kstep * 32 + quad * 8;
            int pc = ko ^ swz;
            short8 af[4], bfr[4];
#pragma unroll
            for (int i = 0; i < 4; i++)
                af[i] = *(const short8*)&As[cur][(wm + i * 16 + l16) * 64 + pc];
#pragma unroll
            for (int j = 0; j < 4; j++)
                bfr[j] = *(const short8*)&Bs[cur][(wn + j * 16 + l16) * 64 + pc];
#pragma unroll
            for (int i = 0; i < 4; i++)
#pragma unroll
                for (int j = 0; j < 4; j++)
                    acc[i][j] = __builtin_amdgcn_mfma_f32_16x16x32_bf16(
                        af[i], bfr[j], acc[i][j], 0, 0, 0);
        }
        __syncthreads();
        cur ^= 1;
    }

    // ---- stream-K fixup: publish partial, last block reduces -------------
#pragma unroll
    for (int i = 0; i < 4; i++)
#pragma unroll
        for (int j = 0; j < 4; j++)
            pbuf[(((size_t)ks * 68 + tile) * 16 + (i * 4 + j)) * 256 + tid] =
                acc[i][j];
    __threadfence();  // agent-scope release of the partial stores
    __syncthreads();
    if (tid == 0) s_last = (atomicAdd(&cnt[tile], 1) == KS - 1);
    __syncthreads();
    if (!s_last) return;
    __threadfence();  // acquire side: see all other blocks' partials

#pragma unroll
    for (int i = 0; i < 4; i++)
#pragma unroll
        for (int j = 0; j < 4; j++) {
            f32x4 s = acc[i][j];
#pragma unroll
            for (int k2 = 0; k2 < KS; ++k2) {
                if (k2 == ks) continue;
                s += pbuf[(((size_t)k2 * 68 + tile) * 16 + (i * 4 + j)) * 256 +
                          tid];
            }
            acc[i][j] = s;
        }
    if (tid == 0) cnt[tile] = 0;  // re-arm for next step (kernel boundary)

    // ---- fused elementwise epilogue --------------------------------------
    if (by < 32) {
#pragma unroll
        for (int i = 0; i < 4; i++)
#pragma unroll
            for (int j = 0; j < 4; j++) {
                int gcol = by * 128 + wn + j * 16 + l16;
#pragma unroll
                for (int rr = 0; rr < 4; ++rr) {
                    int grow = m0 + wm + i * 16 + quad * 4 + rr;
                    size_t p = (size_t)grow * 4096 + gcol;
                    float un = DECAY * u[p] + i_[p] + acc[i][j][rr];
                    u[p] = un;
                    __builtin_nontemporal_store(
                        un, &act[(size_t)grow * (ITER_TIME * 4096) +
                                 (size_t)(t + 1) * 4096 + gcol]);
                    float ar = un > 0.f ? un : 0.f;
                    a_out[p] = __float2bfloat16(ar);
                }
            }
    } else {
#pragma unroll
        for (int i = 0; i < 4; i++)
#pragma unroll
            for (int j = 0; j < 4; j++) {
                int c2 = (by - 32) * 128 + wn + j * 16 + l16;
#pragma unroll
                for (int rr = 0; rr < 4; ++rr) {
                    int grow = m0 + wm + i * 16 + quad * 4 + rr;
                    __builtin_nontemporal_store(
                        acc[i][j][rr],
                        &out[(size_t)grow * (ITER_TIME * 256) +
                             (size_t)t * 256 + c2]);
                }
            }
    }
}

// ---------------------------------------------------------------------------
// Workspace layout (KS selected by ws_size; needs 80MB/63MB/54.5MB):
//   BT   0x0000000  34 MB  bf16 [4352][4096]  (W_r^T rows 0..4095, W_f^T after)
//   i_   0x2200000   4 MB  f32 [256][4096]  (biased drive)
//   u    0x2600000   4 MB  f32 [256][4096]
//   a0   0x2A00000   2 MB  bf16 [256][4096]
//   a1   0x2C00000   2 MB  bf16 [256][4096]
//   pbuf 0x2E00000  KS*4.25 MB  f32x4 [KS][68][16][256]
//   cnt  pbuf_end   272 B  int [68]
//   setup transients (dead before step loop): xb @0x2C00000 (.5 MB, over a1),
//   WiT @0x2C80000 (8 MB, over a1+pbuf head)
// ---------------------------------------------------------------------------
extern "C" void kernel_launch(void* const* d_in, const int* in_sizes, int n_in,
                              void* d_out, int out_size, void* d_ws,
                              size_t ws_size, hipStream_t stream) {
    const float* x = (const float*)d_in[0];    // [256][1024] f32
    const float* Wi = (const float*)d_in[1];   // [1024][4096] f32
    const float* bb = (const float*)d_in[2];   // [4096] f32
    const float* Wr = (const float*)d_in[3];   // [4096][4096] f32
    const float* Wf = (const float*)d_in[4];   // [4096][256] f32

    float* out = (float*)d_out;                        // [256][32][256]
    float* act = out + (size_t)256 * ITER_TIME * 256;  // [256][32][4096]

    int KS = (ws_size >= (size_t)0x5002000)   ? 8
             : (ws_size >= (size_t)0x3F02000) ? 4
                                              : 2;

    char* ws = (char*)d_ws;
    __hip_bfloat16* BT = (__hip_bfloat16*)(ws + 0x0);
    float* i_ = (float*)(ws + 0x2200000);
    float* u = (float*)(ws + 0x2600000);
    __hip_bfloat16* a0 = (__hip_bfloat16*)(ws + 0x2A00000);
    __hip_bfloat16* a1 = (__hip_bfloat16*)(ws + 0x2C00000);
    f32x4* pbuf = (f32x4*)(ws + 0x2E00000);
    int* cnt = (int*)(ws + 0x2E00000 + (size_t)KS * 0x440000);
    __hip_bfloat16* xb = (__hip_bfloat16*)(ws + 0x2C00000);   // transient
    __hip_bfloat16* WiT = (__hip_bfloat16*)(ws + 0x2C80000);  // transient

    conv_f32_bf16<<<1024, 256, 0, stream>>>(x, xb, 256 * 1024, cnt);
    dim3 tb(32, 32);
    transpose_f32_bf16<<<dim3(128, 32), tb, 0, stream>>>(Wi, (__hip_bfloat16*)WiT,
                                                         1024, 4096);
    transpose_f32_bf16<<<dim3(128, 128), tb, 0, stream>>>(Wr, BT, 4096, 4096);
    transpose_f32_bf16<<<dim3(8, 128), tb, 0, stream>>>(
        Wf, BT + (size_t)4096 * 4096, 4096, 256);

    // i_ = x @ W_i + b, fused u0/act0/a0 epilogue
    gemm_wi<<<dim3(2, 32), 256, 0, stream>>>((const ushort_t*)xb,
                                             (const ushort_t*)WiT, bb, i_, u,
                                             a0, act, 1024);

    for (int t = 0; t < ITER_TIME - 1; ++t) {
        const ushort_t* ain = (const ushort_t*)((t & 1) ? a1 : a0);
        __hip_bfloat16* aout = (t & 1) ? a0 : a1;
        if (KS == 8)
            gemm_step<8><<<68 * 8, 256, 0, stream>>>(
                ain, (const ushort_t*)BT, pbuf, cnt, i_, u, aout, out, act, t,
                0);
        else if (KS == 4)
            gemm_step<4><<<68 * 4, 256, 0, stream>>>(
                ain, (const ushort_t*)BT, pbuf, cnt, i_, u, aout, out, act, t,
                0);
        else
            gemm_step<2><<<68 * 2, 256, 0, stream>>>(
                ain, (const ushort_t*)BT, pbuf, cnt, i_, u, aout, out, act, t,
                0);
    }
    {  // t = 31: only the W_f tiles (out[:,31,:]); W_r GEMM is dead work
        int t = ITER_TIME - 1;
        const ushort_t* ain = (const ushort_t*)((t & 1) ? a1 : a0);
        __hip_bfloat16* aout = (t & 1) ? a0 : a1;  // unused (only_f)
        if (KS == 8)
            gemm_step<8><<<4 * 8, 256, 0, stream>>>(ain, (const ushort_t*)BT,
                                                    pbuf, cnt, i_, u, aout,
                                                    out, act, t, 1);
        else if (KS == 4)
            gemm_step<4><<<4 * 4, 256, 0, stream>>>(ain, (const ushort_t*)BT,
                                                    pbuf, cnt, i_, u, aout,
                                                    out, act, t, 1);
        else
            gemm_step<2><<<4 * 2, 256, 0, stream>>>(ain, (const ushort_t*)BT,
                                                    pbuf, cnt, i_, u, aout,
                                                    out, act, t, 1);
    }
}

// Round 4
// 1218.147 us; speedup vs baseline: 3.8437x; 3.8437x over previous
//
#include <hip/hip_runtime.h>
#include <hip/hip_bf16.h>

#define ITER_TIME 32
#define DECAY 0.9f

typedef __attribute__((ext_vector_type(8))) short short8;
typedef __attribute__((ext_vector_type(4))) float f32x4;
typedef __attribute__((ext_vector_type(4))) short short4v;
typedef unsigned short ushort_t;
typedef unsigned int u32;

// global -> LDS direct DMA, 16B per lane. Dest is wave-uniform base + lane*16.
__device__ __forceinline__ void gload16(const ushort_t* g, ushort_t* l) {
    __builtin_amdgcn_global_load_lds(
        (const __attribute__((address_space(1))) u32*)g,
        (__attribute__((address_space(3))) u32*)l, 16, 0, 0);
}

// ---------------------------------------------------------------------------
// Convert f32 -> bf16 elementwise (for x)
// ---------------------------------------------------------------------------
__global__ void conv_f32_bf16(const float* __restrict__ in,
                              __hip_bfloat16* __restrict__ out, int n) {
    int i = blockIdx.x * 256 + threadIdx.x;
    if (i < n) out[i] = __float2bfloat16(in[i]);
}

// ---------------------------------------------------------------------------
// Fused convert + transpose: f32 in [R][C] -> bf16 out [C][R]
// ---------------------------------------------------------------------------
__global__ void transpose_f32_bf16(const float* __restrict__ in,
                                   __hip_bfloat16* __restrict__ out, int R,
                                   int C) {
    __shared__ float tile[32][33];
    int tx = threadIdx.x, ty = threadIdx.y;
    size_t x = blockIdx.x * 32 + tx;  // col in `in`
    size_t y = blockIdx.y * 32 + ty;  // row in `in`
    tile[ty][tx] = in[y * C + x];
    __syncthreads();
    size_t ox = blockIdx.y * 32 + tx;  // col in `out` (= row in `in`)
    size_t oy = blockIdx.x * 32 + ty;  // row in `out` (= col in `in`)
    out[oy * R + ox] = __float2bfloat16(tile[tx][ty]);
}

// ---------------------------------------------------------------------------
// i_ = x @ W_i with fused t=0 elementwise epilogue:
//   i_ = acc + bias ; u0 = i_ ; act[:,0,:] = u0 ; a0 = relu(u0) (bf16)
// grid (2, 32), block 256, 128x128 tile, K=1024.
// ---------------------------------------------------------------------------
__global__ __launch_bounds__(256)
void gemm_wi(const ushort_t* __restrict__ A,   // [256][1024] bf16
             const ushort_t* __restrict__ BT,  // [4096][1024] bf16
             const float* __restrict__ bias, float* __restrict__ i_,
             float* __restrict__ u, __hip_bfloat16* __restrict__ a0,
             float* __restrict__ act, int K) {
    __shared__ __attribute__((aligned(16))) ushort_t As[2][128 * 64];
    __shared__ __attribute__((aligned(16))) ushort_t Bs[2][128 * 64];

    int m0 = blockIdx.x * 128;
    int by = blockIdx.y;
    const ushort_t* Bsrc = BT + (size_t)by * 128 * K;

    int t = threadIdx.x;
    int wave = t >> 6, lane = t & 63;
    int quad = lane >> 4, l16 = lane & 15;
    int wm = (wave >> 1) * 64, wn = (wave & 1) * 64;

    int lr = lane >> 3;
    int lcol = ((lane & 7) ^ lr) << 3;
    const ushort_t* aBase = A + (size_t)(m0 + wave * 32 + lr) * K + lcol;
    const ushort_t* bBase = Bsrc + (size_t)(wave * 32 + lr) * K + lcol;

    f32x4 acc[4][4];
#pragma unroll
    for (int i = 0; i < 4; i++)
#pragma unroll
        for (int j = 0; j < 4; j++) acc[i][j] = (f32x4){0.f, 0.f, 0.f, 0.f};

    int nt = K >> 6;
    int swz = (l16 & 7) << 3;

    auto stage = [&](int buf, int kk) {
#pragma unroll
        for (int i = 0; i < 4; ++i) {
            gload16(aBase + (size_t)(i * 8) * K + kk,
                    &As[buf][(wave * 4 + i) * 512]);
            gload16(bBase + (size_t)(i * 8) * K + kk,
                    &Bs[buf][(wave * 4 + i) * 512]);
        }
    };

    stage(0, 0);
    __syncthreads();
    int cur = 0;
    for (int it = 0; it < nt; ++it) {
        if (it + 1 < nt) stage(cur ^ 1, (it + 1) * 64);
#pragma unroll
        for (int kstep = 0; kstep < 2; ++kstep) {
            int ko = kstep * 32 + quad * 8;
            int pc = ko ^ swz;
            short8 af[4], bfr[4];
#pragma unroll
            for (int i = 0; i < 4; i++)
                af[i] = *(const short8*)&As[cur][(wm + i * 16 + l16) * 64 + pc];
#pragma unroll
            for (int j = 0; j < 4; j++)
                bfr[j] = *(const short8*)&Bs[cur][(wn + j * 16 + l16) * 64 + pc];
#pragma unroll
            for (int i = 0; i < 4; i++)
#pragma unroll
                for (int j = 0; j < 4; j++)
                    acc[i][j] = __builtin_amdgcn_mfma_f32_16x16x32_bf16(
                        af[i], bfr[j], acc[i][j], 0, 0, 0);
        }
        __syncthreads();
        cur ^= 1;
    }

    // Fused t=0 epilogue. C/D layout: col = lane&15, row = quad*4 + reg.
#pragma unroll
    for (int i = 0; i < 4; i++)
#pragma unroll
        for (int j = 0; j < 4; j++) {
            int gcol = by * 128 + wn + j * 16 + l16;
#pragma unroll
            for (int rr = 0; rr < 4; ++rr) {
                int grow = m0 + wm + i * 16 + quad * 4 + rr;
                size_t p = (size_t)grow * 4096 + gcol;
                float iv = acc[i][j][rr] + bias[gcol];
                i_[p] = iv;
                u[p] = iv;
                __builtin_nontemporal_store(
                    iv, &act[(size_t)grow * (ITER_TIME * 4096) + gcol]);
                float ar = iv > 0.f ? iv : 0.f;
                a0[p] = __float2bfloat16(ar);
            }
        }
}

// ---------------------------------------------------------------------------
// Recurrent split-K GEMM: a_t @ [W_r | W_f] -> rp (KS=2 partials) / fp.
// Tile 128x32, KS=2, grid 544 blocks (2m x 136by x 2ks), block 256 (4 waves,
// each wave owns a 32x32 sub-tile). LDS 40 KB -> 4 blocks/CU LDS-legal;
// 544 blocks ~ 2.1/CU resident -> ~8.5 waves/CU pulling HBM.
// XCD m-pair swizzle: blocks i and i+8 share (by,ks) with m=0/1 and land on
// the same XCD (dispatch round-robins blockIdx%8) -> second B read is L2-hit.
// ONLY_F=1: t=31 variant, W_f tiles only (32 blocks).
// ---------------------------------------------------------------------------
template <int ONLY_F>
__global__ __launch_bounds__(256)
void gemm_step(const ushort_t* __restrict__ A,   // a_t [256][4096] bf16
               const ushort_t* __restrict__ BT,  // [4352][4096] bf16 (Wr|Wf)
               float* __restrict__ rp,           // [2][256][4096] f32
               float* __restrict__ fp) {         // [2][256][256] f32
    const int K = 4096, klen = 2048;
    __shared__ __attribute__((aligned(16))) ushort_t As[2][128 * 64];  // 32 KB
    __shared__ __attribute__((aligned(16))) ushort_t Bs[2][32 * 64];   // 8 KB

    int blk = blockIdx.x;
    int by, ks, m;
    if (ONLY_F) {
        by = 128 + (blk >> 2);
        int w = blk & 3;
        m = w & 1;
        ks = w >> 1;
    } else {
        int x = blk & 15, g = blk >> 4;
        int xcd = x & 7;
        m = x >> 3;
        int pair = g * 8 + xcd;  // bijective over [0,272)
        by = pair % 136;
        ks = pair / 136;
    }
    int m0 = m * 128;
    const ushort_t* Bsrc = BT + (size_t)by * 32 * K;

    int tid = threadIdx.x;
    int wave = tid >> 6, lane = tid & 63;
    int quad = lane >> 4, l16 = lane & 15;

    int lr = lane >> 3;                 // row within 8-row staging chunk
    int lcol = ((lane & 7) ^ lr) << 3;  // inverse-swizzled source col
    const ushort_t* aBase = A + (size_t)(m0 + wave * 32 + lr) * K + lcol;
    const ushort_t* bBase = Bsrc + (size_t)(wave * 8 + lr) * K + lcol;

    f32x4 acc[2][2];
#pragma unroll
    for (int i = 0; i < 2; i++)
#pragma unroll
        for (int j = 0; j < 2; j++) acc[i][j] = (f32x4){0.f, 0.f, 0.f, 0.f};

    const int k0 = ks * klen;
    const int nt = klen >> 6;  // 32
    int swz = (l16 & 7) << 3;

    auto stage = [&](int buf, int kk) {
#pragma unroll
        for (int i = 0; i < 4; ++i)  // A: wave stages rows [wave*32+i*8, +8)
            gload16(aBase + (size_t)(i * 8) * K + kk,
                    &As[buf][(wave * 4 + i) * 512]);
        // B: wave stages rows [wave*8, wave*8+8)
        gload16(bBase + kk, &Bs[buf][wave * 512]);
    };

    stage(0, k0);
    __syncthreads();
    int cur = 0;
    for (int it = 0; it < nt; ++it) {
        if (it + 1 < nt) stage(cur ^ 1, k0 + (it + 1) * 64);
#pragma unroll
        for (int kstep = 0; kstep < 2; ++kstep) {
            int ko = kstep * 32 + quad * 8;
            int pc = ko ^ swz;
            short8 af[2], bfr[2];
#pragma unroll
            for (int i = 0; i < 2; i++)
                af[i] = *(const short8*)&As[cur][(wave * 32 + i * 16 + l16) * 64 +
                                                 pc];
#pragma unroll
            for (int j = 0; j < 2; j++)
                bfr[j] = *(const short8*)&Bs[cur][(j * 16 + l16) * 64 + pc];
#pragma unroll
            for (int i = 0; i < 2; i++)
#pragma unroll
                for (int j = 0; j < 2; j++)
                    acc[i][j] = __builtin_amdgcn_mfma_f32_16x16x32_bf16(
                        af[i], bfr[j], acc[i][j], 0, 0, 0);
        }
        __syncthreads();
        cur ^= 1;
    }

    // Epilogue: C/D layout col = lane&15, row = quad*4 + reg
#pragma unroll
    for (int i = 0; i < 2; i++)
#pragma unroll
        for (int j = 0; j < 2; j++) {
            int cl = j * 16 + l16;
#pragma unroll
            for (int rr = 0; rr < 4; ++rr) {
                int grow = m0 + wave * 32 + i * 16 + quad * 4 + rr;
                float v = acc[i][j][rr];
                if (by < 128) {
                    rp[(size_t)ks * (256 * 4096) + (size_t)grow * 4096 +
                       by * 32 + cl] = v;
                } else {
                    fp[(size_t)ks * (256 * 256) + (size_t)grow * 256 +
                       (by - 128) * 32 + cl] = v;
                }
            }
        }
}

// ---------------------------------------------------------------------------
// Per-step elementwise (f32x4): u_t = DECAY*u + i_ + rp0 + rp1 ; act[:,t,:] ;
// a = relu(u_t) bf16 ; out[:,t-1,:] = fp0 + fp1.  t in [1,31].
// fonly=1 (t=32): only the f reduction (out[:,31,:]), grid 64.
// ---------------------------------------------------------------------------
__global__ void elem_step(const float* __restrict__ i_, float* __restrict__ u,
                          __hip_bfloat16* __restrict__ a,
                          const float* __restrict__ rp,
                          const float* __restrict__ fp,
                          float* __restrict__ out, float* __restrict__ act,
                          int t, int fonly) {
    const int NU = 256 * 4096, NU4 = NU / 4;
    const int NF = 256 * 256, NF4 = NF / 4;
    int raw = blockIdx.x * 256 + threadIdx.x;
    int id4 = fonly ? (NU4 + raw) : raw;
    if (id4 >= NU4 + NF4) return;
    if (id4 < NU4) {
        int id = id4 * 4;
        int b = id >> 12, n = id & 4095;
        f32x4 s = *(const f32x4*)&i_[id] + *(const f32x4*)&rp[id] +
                  *(const f32x4*)&rp[NU + id];
        f32x4 un = DECAY * *(const f32x4*)&u[id] + s;
        *(f32x4*)&u[id] = un;
        short4v av;
#pragma unroll
        for (int j = 0; j < 4; ++j) {
            float ar = un[j] > 0.f ? un[j] : 0.f;
            __hip_bfloat16 h = __float2bfloat16(ar);
            av[j] = *(short*)&h;
        }
        *(short4v*)&a[id] = av;
        __builtin_nontemporal_store(
            un, (f32x4*)&act[(size_t)b * (ITER_TIME * 4096) +
                             (size_t)t * 4096 + n]);
    } else {
        int id2 = (id4 - NU4) * 4;
        int b = id2 >> 8, d = id2 & 255;
        f32x4 fv = *(const f32x4*)&fp[id2] + *(const f32x4*)&fp[NF + id2];
        __builtin_nontemporal_store(
            fv, (f32x4*)&out[(size_t)b * (ITER_TIME * 256) +
                             (size_t)(t - 1) * 256 + d]);
    }
}

// ---------------------------------------------------------------------------
// Workspace layout (61 MB peak, matches prior-session footprint):
//   BT   0x0000000  34 MB  bf16 [4352][4096]  (W_r^T | W_f^T)
//   i_   0x2200000   4 MB  f32 [256][4096]  (biased drive)
//   u    0x2600000   4 MB  f32 [256][4096]
//   a    0x2A00000   2 MB  bf16 [256][4096]
//   rp   0x2C00000   8 MB  f32 [2][256][4096]
//   fp   0x3400000  .5 MB  f32 [2][256][256]
//   xb   0x3480000  .5 MB  bf16 [256][1024]   (setup transient)
//   WiT  0x3500000   8 MB  bf16 [4096][1024]  (setup transient)
// ---------------------------------------------------------------------------
extern "C" void kernel_launch(void* const* d_in, const int* in_sizes, int n_in,
                              void* d_out, int out_size, void* d_ws,
                              size_t ws_size, hipStream_t stream) {
    const float* x = (const float*)d_in[0];    // [256][1024] f32
    const float* Wi = (const float*)d_in[1];   // [1024][4096] f32
    const float* bb = (const float*)d_in[2];   // [4096] f32
    const float* Wr = (const float*)d_in[3];   // [4096][4096] f32
    const float* Wf = (const float*)d_in[4];   // [4096][256] f32

    float* out = (float*)d_out;                        // [256][32][256]
    float* act = out + (size_t)256 * ITER_TIME * 256;  // [256][32][4096]

    char* ws = (char*)d_ws;
    __hip_bfloat16* BT = (__hip_bfloat16*)(ws + 0x0);
    float* i_ = (float*)(ws + 0x2200000);
    float* u = (float*)(ws + 0x2600000);
    __hip_bfloat16* a = (__hip_bfloat16*)(ws + 0x2A00000);
    float* rp = (float*)(ws + 0x2C00000);
    float* fp = (float*)(ws + 0x3400000);
    __hip_bfloat16* xb = (__hip_bfloat16*)(ws + 0x3480000);   // transient
    __hip_bfloat16* WiT = (__hip_bfloat16*)(ws + 0x3500000);  // transient

    conv_f32_bf16<<<1024, 256, 0, stream>>>(x, xb, 256 * 1024);
    dim3 tb(32, 32);
    transpose_f32_bf16<<<dim3(128, 32), tb, 0, stream>>>(Wi, WiT, 1024, 4096);
    transpose_f32_bf16<<<dim3(128, 128), tb, 0, stream>>>(Wr, BT, 4096, 4096);
    transpose_f32_bf16<<<dim3(8, 128), tb, 0, stream>>>(
        Wf, BT + (size_t)4096 * 4096, 4096, 256);

    // i_ = x @ W_i + b, fused u0/act0/a0 epilogue
    gemm_wi<<<dim3(2, 32), 256, 0, stream>>>((const ushort_t*)xb,
                                             (const ushort_t*)WiT, bb, i_, u,
                                             a, act, 1024);

    for (int t = 0; t < ITER_TIME - 1; ++t) {
        gemm_step<0><<<544, 256, 0, stream>>>((const ushort_t*)a,
                                              (const ushort_t*)BT, rp, fp);
        elem_step<<<1088, 256, 0, stream>>>(i_, u, a, rp, fp, out, act, t + 1,
                                            0);
    }
    // t = 31: only W_f tiles (out[:,31,:]); W_r GEMM would be dead work
    gemm_step<1><<<32, 256, 0, stream>>>((const ushort_t*)a,
                                         (const ushort_t*)BT, rp, fp);
    elem_step<<<64, 256, 0, stream>>>(i_, u, a, rp, fp, out, act, ITER_TIME,
                                      1);
}

// Round 5
// 1109.612 us; speedup vs baseline: 4.2196x; 1.0978x over previous
//
#include <hip/hip_runtime.h>
#include <hip/hip_bf16.h>

#define ITER_TIME 32
#define DECAY 0.9f

typedef __attribute__((ext_vector_type(8))) short short8;
typedef __attribute__((ext_vector_type(4))) float f32x4;
typedef __attribute__((ext_vector_type(4))) short short4v;
typedef unsigned short ushort_t;
typedef unsigned int u32;

// global -> LDS direct DMA, 16B per lane. Dest is wave-uniform base + lane*16.
__device__ __forceinline__ void gload16(const ushort_t* g, ushort_t* l) {
    __builtin_amdgcn_global_load_lds(
        (const __attribute__((address_space(1))) u32*)g,
        (__attribute__((address_space(3))) u32*)l, 16, 0, 0);
}

// ---------------------------------------------------------------------------
// Convert f32 -> bf16 elementwise (for x)
// ---------------------------------------------------------------------------
__global__ void conv_f32_bf16(const float* __restrict__ in,
                              __hip_bfloat16* __restrict__ out, int n) {
    int i = blockIdx.x * 256 + threadIdx.x;
    if (i < n) out[i] = __float2bfloat16(in[i]);
}

// ---------------------------------------------------------------------------
// Fused convert + transpose: f32 in [R][C] -> bf16 out [C][R]
// ---------------------------------------------------------------------------
__global__ void transpose_f32_bf16(const float* __restrict__ in,
                                   __hip_bfloat16* __restrict__ out, int R,
                                   int C) {
    __shared__ float tile[32][33];
    int tx = threadIdx.x, ty = threadIdx.y;
    size_t x = blockIdx.x * 32 + tx;  // col in `in`
    size_t y = blockIdx.y * 32 + ty;  // row in `in`
    tile[ty][tx] = in[y * C + x];
    __syncthreads();
    size_t ox = blockIdx.y * 32 + tx;  // col in `out` (= row in `in`)
    size_t oy = blockIdx.x * 32 + ty;  // row in `out` (= col in `in`)
    out[oy * R + ox] = __float2bfloat16(tile[tx][ty]);
}

// ---------------------------------------------------------------------------
// i_ = x @ W_i with fused t=0 elementwise epilogue:
//   i_ = acc + bias ; u0 = i_ ; act[:,0,:] = u0 ; a0 = relu(u0) (bf16)
// grid (2, 32), block 256, 128x128 tile, K=1024.
// ---------------------------------------------------------------------------
__global__ __launch_bounds__(256)
void gemm_wi(const ushort_t* __restrict__ A,   // [256][1024] bf16
             const ushort_t* __restrict__ BT,  // [4096][1024] bf16
             const float* __restrict__ bias, float* __restrict__ i_,
             float* __restrict__ u, __hip_bfloat16* __restrict__ a0,
             float* __restrict__ act, int K) {
    __shared__ __attribute__((aligned(16))) ushort_t As[2][128 * 64];
    __shared__ __attribute__((aligned(16))) ushort_t Bs[2][128 * 64];

    int m0 = blockIdx.x * 128;
    int by = blockIdx.y;
    const ushort_t* Bsrc = BT + (size_t)by * 128 * K;

    int t = threadIdx.x;
    int wave = t >> 6, lane = t & 63;
    int quad = lane >> 4, l16 = lane & 15;
    int wm = (wave >> 1) * 64, wn = (wave & 1) * 64;

    int lr = lane >> 3;
    int lcol = ((lane & 7) ^ lr) << 3;
    const ushort_t* aBase = A + (size_t)(m0 + wave * 32 + lr) * K + lcol;
    const ushort_t* bBase = Bsrc + (size_t)(wave * 32 + lr) * K + lcol;

    f32x4 acc[4][4];
#pragma unroll
    for (int i = 0; i < 4; i++)
#pragma unroll
        for (int j = 0; j < 4; j++) acc[i][j] = (f32x4){0.f, 0.f, 0.f, 0.f};

    int nt = K >> 6;
    int swz = (l16 & 7) << 3;

    auto stage = [&](int buf, int kk) {
#pragma unroll
        for (int i = 0; i < 4; ++i) {
            gload16(aBase + (size_t)(i * 8) * K + kk,
                    &As[buf][(wave * 4 + i) * 512]);
            gload16(bBase + (size_t)(i * 8) * K + kk,
                    &Bs[buf][(wave * 4 + i) * 512]);
        }
    };

    stage(0, 0);
    __syncthreads();
    int cur = 0;
    for (int it = 0; it < nt; ++it) {
        if (it + 1 < nt) stage(cur ^ 1, (it + 1) * 64);
#pragma unroll
        for (int kstep = 0; kstep < 2; ++kstep) {
            int ko = kstep * 32 + quad * 8;
            int pc = ko ^ swz;
            short8 af[4], bfr[4];
#pragma unroll
            for (int i = 0; i < 4; i++)
                af[i] = *(const short8*)&As[cur][(wm + i * 16 + l16) * 64 + pc];
#pragma unroll
            for (int j = 0; j < 4; j++)
                bfr[j] = *(const short8*)&Bs[cur][(wn + j * 16 + l16) * 64 + pc];
#pragma unroll
            for (int i = 0; i < 4; i++)
#pragma unroll
                for (int j = 0; j < 4; j++)
                    acc[i][j] = __builtin_amdgcn_mfma_f32_16x16x32_bf16(
                        af[i], bfr[j], acc[i][j], 0, 0, 0);
        }
        __syncthreads();
        cur ^= 1;
    }

    // Fused t=0 epilogue. C/D layout: col = lane&15, row = quad*4 + reg.
#pragma unroll
    for (int i = 0; i < 4; i++)
#pragma unroll
        for (int j = 0; j < 4; j++) {
            int gcol = by * 128 + wn + j * 16 + l16;
#pragma unroll
            for (int rr = 0; rr < 4; ++rr) {
                int grow = m0 + wm + i * 16 + quad * 4 + rr;
                size_t p = (size_t)grow * 4096 + gcol;
                float iv = acc[i][j][rr] + bias[gcol];
                i_[p] = iv;
                u[p] = iv;
                __builtin_nontemporal_store(
                    iv, &act[(size_t)grow * (ITER_TIME * 4096) + gcol]);
                float ar = iv > 0.f ? iv : 0.f;
                a0[p] = __float2bfloat16(ar);
            }
        }
}

// ---------------------------------------------------------------------------
// Recurrent split-K GEMM: a_t @ [W_r | W_f] -> rp (KS=4 partials) / fp.
// Tile 128x64, KS=4, grid 544 (W_r: 512, W_f: 32), block 256 = 4 waves.
// Per wave: 64x32 output (acc[4][2]) -> 6 ds_read_b128 : 8 MFMA per kstep
// (fragment reuse; 0.75 KB LDS traffic per MFMA vs 1.0 at 128x32).
// LDS 48 KB -> 3 blocks/CU cap; 544 blocks ~ 2.1/CU resident.
// XCD pinning: all 8 (m,ks)-siblings of a W_r by-tile land on one XCD
// (blk = (w<<6)|(bg<<3)|xcd, by = xcd + 8*bg) -> each 512 KB B-slice is
// HBM-fetched once per step, then L2-hit for the other 7 blocks.
// ONLY_F=1: t=31 variant, W_f tiles only (32 blocks).
// ---------------------------------------------------------------------------
template <int ONLY_F>
__global__ __launch_bounds__(256)
void gemm_step(const ushort_t* __restrict__ A,   // a_t [256][4096] bf16
               const ushort_t* __restrict__ BT,  // [4352][4096] bf16 (Wr|Wf)
               float* __restrict__ rp,           // [4][256][4096] f32
               float* __restrict__ fp) {         // [4][256][256] f32
    const int K = 4096, klen = 1024;
    __shared__ __attribute__((aligned(16))) ushort_t As[2][128 * 64];  // 32 KB
    __shared__ __attribute__((aligned(16))) ushort_t Bs[2][64 * 64];   // 16 KB

    int blk = blockIdx.x;
    int by, w;
    if (ONLY_F) {
        by = 64 + (blk >> 3);
        w = blk & 7;
    } else if (blk < 512) {
        int xcd = blk & 7, bg = (blk >> 3) & 7;
        w = blk >> 6;
        by = xcd + 8 * bg;  // by % 8 == xcd for all 8 w-siblings
    } else {
        int idx = blk - 512;
        by = 64 + (idx >> 3);
        w = idx & 7;
    }
    int m = w & 1, ks = w >> 1;
    int m0 = m * 128;
    const ushort_t* Bsrc = BT + (size_t)by * 64 * K;

    int tid = threadIdx.x;
    int wave = tid >> 6, lane = tid & 63;
    int quad = lane >> 4, l16 = lane & 15;
    int wm = (wave >> 1) * 64, wn = (wave & 1) * 32;

    int lr = lane >> 3;                 // row within 8-row staging chunk
    int lcol = ((lane & 7) ^ lr) << 3;  // inverse-swizzled source col
    const ushort_t* aBase = A + (size_t)(m0 + wave * 32 + lr) * K + lcol;
    const ushort_t* bBase = Bsrc + (size_t)(wave * 16 + lr) * K + lcol;

    f32x4 acc[4][2];
#pragma unroll
    for (int i = 0; i < 4; i++)
#pragma unroll
        for (int j = 0; j < 2; j++) acc[i][j] = (f32x4){0.f, 0.f, 0.f, 0.f};

    const int k0 = ks * klen;
    const int nt = klen >> 6;  // 16
    int swz = (l16 & 7) << 3;

    auto stage = [&](int buf, int kk) {
#pragma unroll
        for (int i = 0; i < 4; ++i)  // A: wave stages rows [wave*32+i*8, +8)
            gload16(aBase + (size_t)(i * 8) * K + kk,
                    &As[buf][(wave * 4 + i) * 512]);
#pragma unroll
        for (int i = 0; i < 2; ++i)  // B: wave stages rows [wave*16+i*8, +8)
            gload16(bBase + (size_t)(i * 8) * K + kk,
                    &Bs[buf][(wave * 2 + i) * 512]);
    };

    stage(0, k0);
    __syncthreads();
    int cur = 0;
    for (int it = 0; it < nt; ++it) {
        if (it + 1 < nt) stage(cur ^ 1, k0 + (it + 1) * 64);
#pragma unroll
        for (int kstep = 0; kstep < 2; ++kstep) {
            int ko = kstep * 32 + quad * 8;
            int pc = ko ^ swz;
            short8 af[4], bfr[2];
#pragma unroll
            for (int i = 0; i < 4; i++)
                af[i] = *(const short8*)&As[cur][(wm + i * 16 + l16) * 64 + pc];
#pragma unroll
            for (int j = 0; j < 2; j++)
                bfr[j] = *(const short8*)&Bs[cur][(wn + j * 16 + l16) * 64 + pc];
#pragma unroll
            for (int i = 0; i < 4; i++)
#pragma unroll
                for (int j = 0; j < 2; j++)
                    acc[i][j] = __builtin_amdgcn_mfma_f32_16x16x32_bf16(
                        af[i], bfr[j], acc[i][j], 0, 0, 0);
        }
        __syncthreads();
        cur ^= 1;
    }

    // Epilogue: C/D layout col = lane&15, row = quad*4 + reg
#pragma unroll
    for (int i = 0; i < 4; i++)
#pragma unroll
        for (int j = 0; j < 2; j++) {
            int cl = wn + j * 16 + l16;  // 0..63 within the 64-wide tile
#pragma unroll
            for (int rr = 0; rr < 4; ++rr) {
                int grow = m0 + wm + i * 16 + quad * 4 + rr;
                float v = acc[i][j][rr];
                if (by < 64) {
                    rp[(size_t)ks * (256 * 4096) + (size_t)grow * 4096 +
                       by * 64 + cl] = v;
                } else {
                    fp[(size_t)ks * (256 * 256) + (size_t)grow * 256 +
                       (by - 64) * 64 + cl] = v;
                }
            }
        }
}

// ---------------------------------------------------------------------------
// Per-step elementwise (f32x4): u_t = DECAY*u + i_ + sum(rp) ; act[:,t,:] ;
// a = relu(u_t) bf16 ; out[:,t-1,:] = sum(fp).  t in [1,31].
// Partials are read with NON-TEMPORAL loads (read-once; don't evict W_r).
// fonly=1 (t=32): only the f reduction (out[:,31,:]), grid 64.
// ---------------------------------------------------------------------------
__global__ void elem_step(const float* __restrict__ i_, float* __restrict__ u,
                          __hip_bfloat16* __restrict__ a,
                          const float* __restrict__ rp,
                          const float* __restrict__ fp,
                          float* __restrict__ out, float* __restrict__ act,
                          int t, int fonly) {
    const int NU = 256 * 4096, NU4 = NU / 4;
    const int NF = 256 * 256, NF4 = NF / 4;
    int raw = blockIdx.x * 256 + threadIdx.x;
    int id4 = fonly ? (NU4 + raw) : raw;
    if (id4 >= NU4 + NF4) return;
    if (id4 < NU4) {
        int id = id4 * 4;
        int b = id >> 12, n = id & 4095;
        f32x4 s = *(const f32x4*)&i_[id];
#pragma unroll
        for (int k = 0; k < 4; ++k)
            s += __builtin_nontemporal_load(
                (const f32x4*)&rp[(size_t)k * NU + id]);
        f32x4 un = DECAY * *(const f32x4*)&u[id] + s;
        *(f32x4*)&u[id] = un;
        short4v av;
#pragma unroll
        for (int j = 0; j < 4; ++j) {
            float ar = un[j] > 0.f ? un[j] : 0.f;
            __hip_bfloat16 h = __float2bfloat16(ar);
            av[j] = *(short*)&h;
        }
        *(short4v*)&a[id] = av;
        __builtin_nontemporal_store(
            un, (f32x4*)&act[(size_t)b * (ITER_TIME * 4096) +
                             (size_t)t * 4096 + n]);
    } else {
        int id2 = (id4 - NU4) * 4;
        int b = id2 >> 8, d = id2 & 255;
        f32x4 fv = {0.f, 0.f, 0.f, 0.f};
#pragma unroll
        for (int k = 0; k < 4; ++k)
            fv += __builtin_nontemporal_load(
                (const f32x4*)&fp[(size_t)k * NF + id2]);
        __builtin_nontemporal_store(
            fv, (f32x4*)&out[(size_t)b * (ITER_TIME * 256) +
                             (size_t)(t - 1) * 256 + d]);
    }
}

// ---------------------------------------------------------------------------
// Workspace layout (61.5 MB peak — proven footprint):
//   BT   0x0000000  34 MB  bf16 [4352][4096]  (W_r^T | W_f^T)
//   i_   0x2200000   4 MB  f32 [256][4096]  (biased drive)
//   u    0x2600000   4 MB  f32 [256][4096]
//   a    0x2A00000   2 MB  bf16 [256][4096]
//   rp   0x2C00000  16 MB  f32 [4][256][4096]  (WiT transiently lives here)
//   fp   0x3C00000   1 MB  f32 [4][256][256]   (xb transiently lives here)
// ---------------------------------------------------------------------------
extern "C" void kernel_launch(void* const* d_in, const int* in_sizes, int n_in,
                              void* d_out, int out_size, void* d_ws,
                              size_t ws_size, hipStream_t stream) {
    const float* x = (const float*)d_in[0];    // [256][1024] f32
    const float* Wi = (const float*)d_in[1];   // [1024][4096] f32
    const float* bb = (const float*)d_in[2];   // [4096] f32
    const float* Wr = (const float*)d_in[3];   // [4096][4096] f32
    const float* Wf = (const float*)d_in[4];   // [4096][256] f32

    float* out = (float*)d_out;                        // [256][32][256]
    float* act = out + (size_t)256 * ITER_TIME * 256;  // [256][32][4096]

    char* ws = (char*)d_ws;
    __hip_bfloat16* BT = (__hip_bfloat16*)(ws + 0x0);
    float* i_ = (float*)(ws + 0x2200000);
    float* u = (float*)(ws + 0x2600000);
    __hip_bfloat16* a = (__hip_bfloat16*)(ws + 0x2A00000);
    float* rp = (float*)(ws + 0x2C00000);
    float* fp = (float*)(ws + 0x3C00000);
    __hip_bfloat16* WiT = (__hip_bfloat16*)(ws + 0x2C00000);  // transient in rp
    __hip_bfloat16* xb = (__hip_bfloat16*)(ws + 0x3C00000);   // transient in fp

    conv_f32_bf16<<<1024, 256, 0, stream>>>(x, xb, 256 * 1024);
    dim3 tb(32, 32);
    transpose_f32_bf16<<<dim3(128, 32), tb, 0, stream>>>(Wi, WiT, 1024, 4096);
    transpose_f32_bf16<<<dim3(128, 128), tb, 0, stream>>>(Wr, BT, 4096, 4096);
    transpose_f32_bf16<<<dim3(8, 128), tb, 0, stream>>>(
        Wf, BT + (size_t)4096 * 4096, 4096, 256);

    // i_ = x @ W_i + b, fused u0/act0/a0 epilogue
    gemm_wi<<<dim3(2, 32), 256, 0, stream>>>((const ushort_t*)xb,
                                             (const ushort_t*)WiT, bb, i_, u,
                                             a, act, 1024);

    for (int t = 0; t < ITER_TIME - 1; ++t) {
        gemm_step<0><<<544, 256, 0, stream>>>((const ushort_t*)a,
                                              (const ushort_t*)BT, rp, fp);
        elem_step<<<1088, 256, 0, stream>>>(i_, u, a, rp, fp, out, act, t + 1,
                                            0);
    }
    // t = 31: only W_f tiles (out[:,31,:]); W_r GEMM would be dead work
    gemm_step<1><<<32, 256, 0, stream>>>((const ushort_t*)a,
                                         (const ushort_t*)BT, rp, fp);
    elem_step<<<64, 256, 0, stream>>>(i_, u, a, rp, fp, out, act, ITER_TIME,
                                      1);
}